// Round 1
// baseline (513.956 us; speedup 1.0000x reference)
//
#include <hip/hip_runtime.h>
#include <math.h>

// ---------------------------------------------------------------------------
// MultiLoss + JSD fused pipeline. R5:
//  * k_main: R4 streaming-CE retained. NEW: all 22 float4 loads made
//    unconditional (row clamped to B-1, word clamped to 41; duplicated data
//    provably masked out by compile-time cem/msm masks) and pinned BEFORE the
//    compute with __builtin_amdgcn_sched_barrier(0). R4's VGPR_Count=52 showed
//    the compiler sank loads into compute -> latency-bound (VALU 19%, HBM 17%,
//    occupancy 35%: nothing saturated). Now ~22 loads in flight per wave;
//    __launch_bounds__(256,2) gives regalloc room (~120 VGPR -> 4 waves/SIMD).
//  * k_hist: element-linearized grid-stride (coalesced enc reads) + runtime
//    block count hb (up to 512, capped by ws_size) instead of fixed 64 blocks
//    -> all 256 CUs active. 16-bit packing safe: per-block/column <= B/hb.
//  * k_merge: runtime hb.
// ---------------------------------------------------------------------------

#define BINS 800
#define NHCOLS 10
#define HB_MAX 512        // histogram partial blocks (runtime-capped by ws_size)

// workspace layout (uint32 indices)
#define MIN_OFF 0         // 11 ordered-uint mins
#define MAX_OFF 16        // 11 ordered-uint maxs
#define CNT_OFF 32        // male, female counts
#define SUM_OFF 34        // mse_sum, ce_sum (float)
#define MH_OFF  64        // 8000 merged male hist
#define FH_OFF  8064      // 8000 merged female hist
#define PART_OFF 16384    // hb x 8000 packed partial hists
#define WS_INIT_U32 64

__device__ __forceinline__ unsigned f2ord(float f) {
  unsigned u = __float_as_uint(f);
  return (u & 0x80000000u) ? ~u : (u | 0x80000000u);
}
__device__ __forceinline__ float ord2f(unsigned e) {
  return __uint_as_float((e & 0x80000000u) ? (e & 0x7FFFFFFFu) : ~e);
}

__global__ void k_init(unsigned* __restrict__ ws) {
  int i = blockIdx.x * blockDim.x + threadIdx.x;
  if (i < WS_INIT_U32) ws[i] = (i < 11) ? 0xFFFFFFFFu : 0u;
}

// per-column min/max of data_encoded + male/female counts from label.
__global__ __launch_bounds__(256) void k_minmax(const float* __restrict__ enc,
                                                const float* __restrict__ lab,
                                                unsigned* __restrict__ ws, int B) {
  const int tid    = blockIdx.x * blockDim.x + threadIdx.x;
  const int stride = gridDim.x * blockDim.x;   // 352*256 = 90112 = 11*8192
  const int c      = tid % 11;
  unsigned mn = 0xFFFFFFFFu, mx = 0u;
  const long long total = (long long)B * 11;
  for (long long i = tid; i < total; i += stride) {
    unsigned e = f2ord(enc[i]);
    mn = mn < e ? mn : e;
    mx = mx > e ? mx : e;
  }
  __shared__ unsigned smn[11], smx[11], scnt[2];
  if (threadIdx.x < 11) { smn[threadIdx.x] = 0xFFFFFFFFu; smx[threadIdx.x] = 0u; }
  if (threadIdx.x < 2)  scnt[threadIdx.x] = 0u;
  __syncthreads();
  atomicMin(&smn[c], mn);
  atomicMax(&smx[c], mx);
  unsigned m = 0, f = 0;
  for (int i = tid; i < B; i += stride) {
    float v = lab[i];
    m += (v == 0.0f);
    f += (v == 1.0f);
  }
  atomicAdd(&scnt[0], m);
  atomicAdd(&scnt[1], f);
  __syncthreads();
  if (threadIdx.x < 11) {
    atomicMin(&ws[MIN_OFF + threadIdx.x], smn[threadIdx.x]);
    atomicMax(&ws[MAX_OFF + threadIdx.x], smx[threadIdx.x]);
  }
  if (threadIdx.x == 11) atomicAdd(&ws[CNT_OFF + 0], scnt[0]);
  if (threadIdx.x == 12) atomicAdd(&ws[CNT_OFF + 1], scnt[1]);
}

// gendered histograms, male packed lo16 / female hi16; per-block partials
// stored to ws (no global atomics), merged by k_merge. Element-linearized
// grid-stride: lane i reads enc word i (fully coalesced). Per-block
// per-column count <= ~B/hb (+1), fits 16 bits for hb >= 8 at B=262144.
__global__ __launch_bounds__(256) void k_hist(const float* __restrict__ enc,
                                              const float* __restrict__ lab,
                                              unsigned* __restrict__ ws, int B, int hb) {
  __shared__ unsigned h[2][NHCOLS * BINS];
  __shared__ float smn[NHCOLS], srng[NHCOLS];
  unsigned* hf = &h[0][0];
  for (int i = threadIdx.x; i < 2 * NHCOLS * BINS; i += blockDim.x) hf[i] = 0u;
  if (threadIdx.x < NHCOLS) {
    float lo = ord2f(ws[MIN_OFF + threadIdx.x]);
    float hi = ord2f(ws[MAX_OFF + threadIdx.x]);
    smn[threadIdx.x] = lo;
    srng[threadIdx.x] = hi - lo;
  }
  __syncthreads();
  const int sub = (threadIdx.x >> 6) & 1;
  const int total  = B * 11;
  const int stride = hb << 8;
  for (int i = (blockIdx.x << 8) + threadIdx.x; i < total; i += stride) {
    const int r = i / 11;
    const int c = i - r * 11;
    if (c < NHCOLS) {
      float lv = lab[r];
      unsigned add = (lv == 0.0f) ? 1u : ((lv == 1.0f) ? 0x10000u : 0u);
      if (add) {
        float t = (enc[i] - smn[c]) / srng[c];   // IEEE div, matches numpy
        int b = (int)floorf(t * 800.0f);
        b = b < 0 ? 0 : (b > BINS - 1 ? BINS - 1 : b);
        atomicAdd(&h[sub][c * BINS + b], add);
      }
    }
  }
  __syncthreads();
  for (int i = threadIdx.x; i < NHCOLS * BINS; i += blockDim.x)
    ws[PART_OFF + (size_t)blockIdx.x * (NHCOLS * BINS) + i] = h[0][i] + h[1][i];
}

__global__ __launch_bounds__(256) void k_merge(unsigned* __restrict__ ws, int hb) {
  int i = blockIdx.x * blockDim.x + threadIdx.x;
  if (i >= NHCOLS * BINS) return;
  unsigned m = 0, f = 0;
  const unsigned* p = ws + PART_OFF + i;
  for (int q = 0; q < hb; ++q) {
    unsigned v = p[(size_t)q * (NHCOLS * BINS)];
    m += v & 0xFFFFu;
    f += v >> 16;
  }
  ws[MH_OFF + i] = m;
  ws[FH_OFF + i] = f;
}

// ---- column classification (compile-time) ----
__host__ __device__ constexpr int slice_of(int c) {
  return (c>=1&&c<10)?0:(c>=12&&c<29)?1:(c>=30&&c<33)?2:(c>=33&&c<40)?3:
         (c>=40&&c<64)?4:(c>=64&&c<79)?5:(c>=79&&c<84)?6:(c>=84&&c<94)?7:
         (c>=94&&c<96)?8:(c>=96&&c<99)?9:(c>=99&&c<105)?10:(c>=105&&c<113)?11:
         (c>=116&&c<122)?12:(c>=122&&c<128)?13:(c>=128&&c<151)?14:
         (c>=151&&c<159)?15:(c>=160&&c<165)?16:-1;
}
__host__ __device__ constexpr bool mse_of(int c) {
  return c==0||c==10||c==11||c==29||c==113||c==114||c==115||c==159||
         c==165||c==166||c==167;
}

// One register element (window I, sub-elem K). Lane j of the quad holds
// column 16I+4j+K; masks over j are compile-time -> branchless cndmask+add.
template<int I, int K>
__device__ __forceinline__ void elem(const float (&d)[11][4], const float (&t)[11][4],
                                     float (&s)[17], float &dot, float &mse, int j) {
  constexpr int c0 = 16*I + K, c1 = c0+4, c2 = c0+8, c3 = c0+12;
  constexpr int cem = ((c0<168 && slice_of(c0)>=0)?1:0) |
                      ((c1<168 && slice_of(c1)>=0)?2:0) |
                      ((c2<168 && slice_of(c2)>=0)?4:0) |
                      ((c3<168 && slice_of(c3)>=0)?8:0);
  constexpr int msm = ((c0<168 && mse_of(c0))?1:0) | ((c1<168 && mse_of(c1))?2:0) |
                      ((c2<168 && mse_of(c2))?4:0) | ((c3<168 && mse_of(c3))?8:0);
  const float dv = d[I][K], tv = t[I][K];
  if constexpr (cem != 0) {
    float e = __expf(dv);
    if constexpr (cem & 1) s[slice_of(c0)] += (j == 0) ? e : 0.0f;
    if constexpr (cem & 2) s[slice_of(c1)] += (j == 1) ? e : 0.0f;
    if constexpr (cem & 4) s[slice_of(c2)] += (j == 2) ? e : 0.0f;
    if constexpr (cem & 8) s[slice_of(c3)] += (j == 3) ? e : 0.0f;
    dot += ((cem >> j) & 1) ? tv * dv : 0.0f;
  }
  if constexpr (msm != 0) {
    float df = dv - tv;
    mse += ((msm >> j) & 1) ? df * df : 0.0f;
  }
}

template<int I>
__device__ __forceinline__ void elem_row(const float (&d)[11][4], const float (&t)[11][4],
                                         float (&s)[17], float &dot, float &mse, int j) {
  elem<I,0>(d, t, s, dot, mse, j);
  elem<I,1>(d, t, s, dot, mse, j);
  elem<I,2>(d, t, s, dot, mse, j);
  elem<I,3>(d, t, s, dot, mse, j);
}

// quad-per-row: lane j of a row loads words 4i+j (contiguous 64B per quad
// per window). All 22 loads unconditional (row clamped to B-1, word clamped
// to 41 -- duplicated values are never accumulated: the cem/msm bits for
// those (lane, window) combos are compile-time zero, and invalid rows are
// masked at the end). sched_barrier(0) pins loads before compute so ~22
// VMEM ops stay in flight per wave (R4 had VGPR=52: loads were sunk into
// compute -> latency-bound).
__global__ __launch_bounds__(256, 2) void k_main(const float* __restrict__ dec,
                                                 const float* __restrict__ tru,
                                                 float* __restrict__ wsf, int B) {
  const int lane = threadIdx.x & 63;
  const int wid  = threadIdx.x >> 6;
  const int j    = lane & 3;
  const int row  = blockIdx.x * 64 + (wid << 4) + (lane >> 2);
  const bool valid = row < B;
  const int rowc = valid ? row : (B - 1);

  float d[11][4], t[11][4];
  const float4* d4 = (const float4*)(dec + (size_t)rowc * 168);
  const float4* t4 = (const float4*)(tru + (size_t)rowc * 168);
#pragma unroll
  for (int i = 0; i < 11; ++i) {
    int w = 4 * i + j;
    w = w > 41 ? 41 : w;                 // j>=2 of window 10: dup load, never used
    const float4 dv = d4[w];
    const float4 tv = t4[w];
    d[i][0] = dv.x; d[i][1] = dv.y; d[i][2] = dv.z; d[i][3] = dv.w;
    t[i][0] = tv.x; t[i][1] = tv.y; t[i][2] = tv.z; t[i][3] = tv.w;
  }
  __builtin_amdgcn_sched_barrier(0);     // keep all loads issued before compute

  float s[17];
#pragma unroll
  for (int k = 0; k < 17; ++k) s[k] = 0.0f;
  float dot = 0.0f, mse = 0.0f;

  elem_row<0>(d, t, s, dot, mse, j);
  elem_row<1>(d, t, s, dot, mse, j);
  elem_row<2>(d, t, s, dot, mse, j);
  elem_row<3>(d, t, s, dot, mse, j);
  elem_row<4>(d, t, s, dot, mse, j);
  elem_row<5>(d, t, s, dot, mse, j);
  elem_row<6>(d, t, s, dot, mse, j);
  elem_row<7>(d, t, s, dot, mse, j);
  elem_row<8>(d, t, s, dot, mse, j);
  elem_row<9>(d, t, s, dot, mse, j);
  elem_row<10>(d, t, s, dot, mse, j);

  // quad allreduce: 34 + 2 independent shuffles
  dot += __shfl_xor(dot, 1, 64);
  dot += __shfl_xor(dot, 2, 64);
#pragma unroll
  for (int k = 0; k < 17; ++k) {
    s[k] += __shfl_xor(s[k], 1, 64);
    s[k] += __shfl_xor(s[k], 2, 64);
  }
  float ce = -dot;
#pragma unroll
  for (int k = 0; k < 17; ++k) ce += __logf(s[k]);

  // ce replicated across quad -> count once; mask invalid rows.
  ce  = (valid && j == 0) ? ce : 0.0f;
  mse = valid ? mse : 0.0f;

  __shared__ float sm[4], sc[4];
#pragma unroll
  for (int off = 32; off > 0; off >>= 1) {
    mse += __shfl_down(mse, off, 64);
    ce  += __shfl_down(ce, off, 64);
  }
  if (lane == 0) { sm[wid] = mse; sc[wid] = ce; }
  __syncthreads();
  if (threadIdx.x == 0) {
    atomicAdd(&wsf[SUM_OFF + 0], sm[0] + sm[1] + sm[2] + sm[3]);
    atomicAdd(&wsf[SUM_OFF + 1], sc[0] + sc[1] + sc[2] + sc[3]);
  }
}

__global__ __launch_bounds__(256) void k_final(const unsigned* __restrict__ ws,
                                               float* __restrict__ out, int B) {
  const float* wsf = (const float*)ws;
  float male   = (float)ws[CNT_OFF + 0];
  float female = (float)ws[CNT_OFF + 1];
  float local = 0.0f;
  for (int i = threadIdx.x; i < NHCOLS * BINS; i += blockDim.x) {
    float mh  = (float)ws[MH_OFF + i] / male;
    float fh  = (float)ws[FH_OFF + i] / female;
    float mid = 0.5f * (mh + fh);
    if (mh > 0.0f) local += mh * logf((mh + 1e-12f) / (mid + 1e-12f));
    if (fh > 0.0f) local += fh * logf((fh + 1e-12f) / (mid + 1e-12f));
  }
  __shared__ float s[4];
  int lane = threadIdx.x & 63, wid = threadIdx.x >> 6;
#pragma unroll
  for (int off = 32; off > 0; off >>= 1) local += __shfl_down(local, off, 64);
  if (lane == 0) s[wid] = local;
  __syncthreads();
  if (threadIdx.x == 0) {
    float kld   = 0.5f * (s[0] + s[1] + s[2] + s[3]);
    float mse   = wsf[SUM_OFF + 0] / (float)B;
    float ce    = wsf[SUM_OFF + 1] / (float)B;
    float multi = 0.9f * (mse + ce) + 0.1f * kld;
    out[0] = multi;
    out[1] = mse;
    out[2] = ce;
    out[3] = 0.1f * kld;
  }
}

extern "C" void kernel_launch(void* const* d_in, const int* in_sizes, int n_in,
                              void* d_out, int out_size, void* d_ws, size_t ws_size,
                              hipStream_t stream) {
  (void)n_in; (void)out_size;
  const float* enc = (const float*)d_in[0];
  const float* dec = (const float*)d_in[1];
  const float* tru = (const float*)d_in[2];
  const float* lab = (const float*)d_in[3];
  const int B = in_sizes[3];                 // label_true is [B,1]
  unsigned* ws = (unsigned*)d_ws;
  float* out = (float*)d_out;

  // runtime histogram-partial block count, capped by workspace capacity
  int hb = HB_MAX;
  {
    size_t avail = ws_size / 4;
    if (avail > (size_t)PART_OFF) {
      size_t cap = (avail - (size_t)PART_OFF) / (size_t)(NHCOLS * BINS);
      if ((size_t)hb > cap) hb = (int)cap;
    } else {
      hb = 1;
    }
    if (hb < 1) hb = 1;
  }

  hipLaunchKernelGGL(k_init, dim3(1), dim3(64), 0, stream, ws);
  hipLaunchKernelGGL(k_minmax, dim3(352), dim3(256), 0, stream, enc, lab, ws, B);
  hipLaunchKernelGGL(k_hist, dim3(hb), dim3(256), 0, stream, enc, lab, ws, B, hb);
  hipLaunchKernelGGL(k_merge, dim3((NHCOLS * BINS + 255) / 256), dim3(256), 0, stream, ws, hb);
  hipLaunchKernelGGL(k_main, dim3((B + 63) / 64), dim3(256), 0, stream,
                     dec, tru, (float*)ws, B);
  hipLaunchKernelGGL(k_final, dim3(1), dim3(256), 0, stream, ws, out, B);
}

// Round 2
// 443.006 us; speedup vs baseline: 1.1602x; 1.1602x over previous
//
#include <hip/hip_runtime.h>
#include <math.h>

// ---------------------------------------------------------------------------
// MultiLoss + JSD fused pipeline. R6:
//  * k_main: loads pinned via asm volatile("" : "+v"(x)) on all 88 loaded
//    floats. R5's sched_barrier(0) failed (VGPR stayed 48 -> loads were sunk
//    at IR level before the MIR scheduler; 88 live floats can't fit in 48
//    VGPRs). The asm pin is a DATA dependency: loads cannot sink past a use
//    of their result, so all 22 float4 loads issue before compute (~22 VMEM
//    in flight/wave -> BW-bound instead of latency-bound).
//    __launch_bounds__(256,3): VGPR cap ~168, no spill at ~115 live.
//  * k_hist: 256 fixed blocks (ws-size independent), element-linear coalesced
//    enc reads, incremental (r,c) stepping (no div in loop), per-block LDS
//    hist (packed m|f<<16, max 1024/bin/block), skip-zero global atomicAdd
//    merge into MH/FH. k_merge kernel DELETED (R5 regression source: hb was
//    ws-capped back to 64 + per-element div).
//  * k_main epilogue: 64 padded atomic staging slots (was 2 hot addresses).
// ---------------------------------------------------------------------------

#define BINS 800
#define NHCOLS 10
#define HBLK 256          // histogram blocks (1 per CU)

// workspace layout (uint32 indices)
#define MIN_OFF 0         // 11 ordered-uint mins
#define MAX_OFF 16        // 11 ordered-uint maxs
#define CNT_OFF 32        // male, female counts
#define MH_OFF  64        // 8000 merged male hist
#define FH_OFF  8064      // 8000 merged female hist
#define SUM2_OFF 16384    // 64 mse slots (stride 32) then 64 ce slots (stride 32)
#define SUM2_CE  (SUM2_OFF + 2048)
#define WS_TOTAL_U32 20480

__device__ __forceinline__ unsigned f2ord(float f) {
  unsigned u = __float_as_uint(f);
  return (u & 0x80000000u) ? ~u : (u | 0x80000000u);
}
__device__ __forceinline__ float ord2f(unsigned e) {
  return __uint_as_float((e & 0x80000000u) ? (e & 0x7FFFFFFFu) : ~e);
}

__global__ void k_init(unsigned* __restrict__ ws) {
  int i = blockIdx.x * blockDim.x + threadIdx.x;
  if (i < WS_TOTAL_U32) ws[i] = (i < 11) ? 0xFFFFFFFFu : 0u;
}

// per-column min/max of data_encoded + male/female counts from label.
__global__ __launch_bounds__(256) void k_minmax(const float* __restrict__ enc,
                                                const float* __restrict__ lab,
                                                unsigned* __restrict__ ws, int B) {
  const int tid    = blockIdx.x * blockDim.x + threadIdx.x;
  const int stride = gridDim.x * blockDim.x;   // 352*256 = 90112 = 11*8192
  const int c      = tid % 11;
  unsigned mn = 0xFFFFFFFFu, mx = 0u;
  const long long total = (long long)B * 11;
  for (long long i = tid; i < total; i += stride) {
    unsigned e = f2ord(enc[i]);
    mn = mn < e ? mn : e;
    mx = mx > e ? mx : e;
  }
  __shared__ unsigned smn[11], smx[11], scnt[2];
  if (threadIdx.x < 11) { smn[threadIdx.x] = 0xFFFFFFFFu; smx[threadIdx.x] = 0u; }
  if (threadIdx.x < 2)  scnt[threadIdx.x] = 0u;
  __syncthreads();
  atomicMin(&smn[c], mn);
  atomicMax(&smx[c], mx);
  unsigned m = 0, f = 0;
  for (int i = tid; i < B; i += stride) {
    float v = lab[i];
    m += (v == 0.0f);
    f += (v == 1.0f);
  }
  atomicAdd(&scnt[0], m);
  atomicAdd(&scnt[1], f);
  __syncthreads();
  if (threadIdx.x < 11) {
    atomicMin(&ws[MIN_OFF + threadIdx.x], smn[threadIdx.x]);
    atomicMax(&ws[MAX_OFF + threadIdx.x], smx[threadIdx.x]);
  }
  if (threadIdx.x == 11) atomicAdd(&ws[CNT_OFF + 0], scnt[0]);
  if (threadIdx.x == 12) atomicAdd(&ws[CNT_OFF + 1], scnt[1]);
}

// gendered histograms, male packed lo16 / female hi16 in per-block LDS hist
// (per-block per-bin count <= B/HBLK = 1024, fits 16 bits), merged into
// global MH/FH with skip-zero atomics. Element-linear grid-stride: lane i
// reads enc word i (fully coalesced); (r,c) updated incrementally.
__global__ __launch_bounds__(256) void k_hist(const float* __restrict__ enc,
                                              const float* __restrict__ lab,
                                              unsigned* __restrict__ ws, int B) {
  __shared__ unsigned h[2][NHCOLS * BINS];
  __shared__ float smn[NHCOLS], srng[NHCOLS];
  unsigned* hf = &h[0][0];
  for (int i = threadIdx.x; i < 2 * NHCOLS * BINS; i += blockDim.x) hf[i] = 0u;
  if (threadIdx.x < NHCOLS) {
    float lo = ord2f(ws[MIN_OFF + threadIdx.x]);
    float hi = ord2f(ws[MAX_OFF + threadIdx.x]);
    smn[threadIdx.x] = lo;
    srng[threadIdx.x] = hi - lo;
  }
  __syncthreads();
  const int sub    = (threadIdx.x >> 6) & 1;
  const int total  = B * 11;
  const int stride = HBLK * 256;               // 65536
  const int qs     = stride / 11;              // uniform
  const int rs     = stride % 11;
  int i = blockIdx.x * 256 + threadIdx.x;
  int r = i / 11;                              // one div total
  int c = i - r * 11;
  for (; i < total; i += stride) {
    if (c < NHCOLS) {
      float lv = lab[r];
      unsigned add = (lv == 0.0f) ? 1u : ((lv == 1.0f) ? 0x10000u : 0u);
      if (add) {
        float t = (enc[i] - smn[c]) / srng[c]; // IEEE div, matches numpy
        int b = (int)floorf(t * 800.0f);
        b = b < 0 ? 0 : (b > BINS - 1 ? BINS - 1 : b);
        atomicAdd(&h[sub][c * BINS + b], add);
      }
    }
    r += qs; c += rs;
    if (c >= 11) { c -= 11; ++r; }
  }
  __syncthreads();
  for (int k = threadIdx.x; k < NHCOLS * BINS; k += blockDim.x) {
    unsigned v = h[0][k] + h[1][k];
    unsigned m = v & 0xFFFFu, f = v >> 16;
    if (m) atomicAdd(&ws[MH_OFF + k], m);
    if (f) atomicAdd(&ws[FH_OFF + k], f);
  }
}

// ---- column classification (compile-time) ----
__host__ __device__ constexpr int slice_of(int c) {
  return (c>=1&&c<10)?0:(c>=12&&c<29)?1:(c>=30&&c<33)?2:(c>=33&&c<40)?3:
         (c>=40&&c<64)?4:(c>=64&&c<79)?5:(c>=79&&c<84)?6:(c>=84&&c<94)?7:
         (c>=94&&c<96)?8:(c>=96&&c<99)?9:(c>=99&&c<105)?10:(c>=105&&c<113)?11:
         (c>=116&&c<122)?12:(c>=122&&c<128)?13:(c>=128&&c<151)?14:
         (c>=151&&c<159)?15:(c>=160&&c<165)?16:-1;
}
__host__ __device__ constexpr bool mse_of(int c) {
  return c==0||c==10||c==11||c==29||c==113||c==114||c==115||c==159||
         c==165||c==166||c==167;
}

// One register element (window I, sub-elem K). Lane j of the quad holds
// column 16I+4j+K; masks over j are compile-time -> branchless cndmask+add.
template<int I, int K>
__device__ __forceinline__ void elem(const float (&d)[11][4], const float (&t)[11][4],
                                     float (&s)[17], float &dot, float &mse, int j) {
  constexpr int c0 = 16*I + K, c1 = c0+4, c2 = c0+8, c3 = c0+12;
  constexpr int cem = ((c0<168 && slice_of(c0)>=0)?1:0) |
                      ((c1<168 && slice_of(c1)>=0)?2:0) |
                      ((c2<168 && slice_of(c2)>=0)?4:0) |
                      ((c3<168 && slice_of(c3)>=0)?8:0);
  constexpr int msm = ((c0<168 && mse_of(c0))?1:0) | ((c1<168 && mse_of(c1))?2:0) |
                      ((c2<168 && mse_of(c2))?4:0) | ((c3<168 && mse_of(c3))?8:0);
  const float dv = d[I][K], tv = t[I][K];
  if constexpr (cem != 0) {
    float e = __expf(dv);
    if constexpr (cem & 1) s[slice_of(c0)] += (j == 0) ? e : 0.0f;
    if constexpr (cem & 2) s[slice_of(c1)] += (j == 1) ? e : 0.0f;
    if constexpr (cem & 4) s[slice_of(c2)] += (j == 2) ? e : 0.0f;
    if constexpr (cem & 8) s[slice_of(c3)] += (j == 3) ? e : 0.0f;
    dot += ((cem >> j) & 1) ? tv * dv : 0.0f;
  }
  if constexpr (msm != 0) {
    float df = dv - tv;
    mse += ((msm >> j) & 1) ? df * df : 0.0f;
  }
}

template<int I>
__device__ __forceinline__ void elem_row(const float (&d)[11][4], const float (&t)[11][4],
                                         float (&s)[17], float &dot, float &mse, int j) {
  elem<I,0>(d, t, s, dot, mse, j);
  elem<I,1>(d, t, s, dot, mse, j);
  elem<I,2>(d, t, s, dot, mse, j);
  elem<I,3>(d, t, s, dot, mse, j);
}

// quad-per-row: lane j of a row loads words 4i+j (contiguous 64B per quad
// per window). All 22 loads unconditional (row clamped to B-1, word clamped
// to 41; duplicated values never accumulated -- their cem/msm bits are
// compile-time zero, invalid rows masked at the end). Loads pinned live via
// empty asm ("+v") on every loaded float: a data dependency no IR pass can
// sink a load past, so all 22 loads are in flight before compute starts.
__global__ __launch_bounds__(256, 3) void k_main(const float* __restrict__ dec,
                                                 const float* __restrict__ tru,
                                                 float* __restrict__ wsf, int B) {
  const int lane = threadIdx.x & 63;
  const int wid  = threadIdx.x >> 6;
  const int j    = lane & 3;
  const int row  = blockIdx.x * 64 + (wid << 4) + (lane >> 2);
  const bool valid = row < B;
  const int rowc = valid ? row : (B - 1);

  float d[11][4], t[11][4];
  const float4* d4 = (const float4*)(dec + (size_t)rowc * 168);
  const float4* t4 = (const float4*)(tru + (size_t)rowc * 168);
#pragma unroll
  for (int i = 0; i < 11; ++i) {
    int w = 4 * i + j;
    w = w > 41 ? 41 : w;                 // j>=2 of window 10: dup load, never used
    const float4 dv = d4[w];
    const float4 tv = t4[w];
    d[i][0] = dv.x; d[i][1] = dv.y; d[i][2] = dv.z; d[i][3] = dv.w;
    t[i][0] = tv.x; t[i][1] = tv.y; t[i][2] = tv.z; t[i][3] = tv.w;
  }
  // Pin every loaded value live HERE. Forces all loads issued before compute.
#pragma unroll
  for (int i = 0; i < 11; ++i) {
    asm volatile("" : "+v"(d[i][0]), "+v"(d[i][1]), "+v"(d[i][2]), "+v"(d[i][3]),
                      "+v"(t[i][0]), "+v"(t[i][1]), "+v"(t[i][2]), "+v"(t[i][3]));
  }

  float s[17];
#pragma unroll
  for (int k = 0; k < 17; ++k) s[k] = 0.0f;
  float dot = 0.0f, mse = 0.0f;

  elem_row<0>(d, t, s, dot, mse, j);
  elem_row<1>(d, t, s, dot, mse, j);
  elem_row<2>(d, t, s, dot, mse, j);
  elem_row<3>(d, t, s, dot, mse, j);
  elem_row<4>(d, t, s, dot, mse, j);
  elem_row<5>(d, t, s, dot, mse, j);
  elem_row<6>(d, t, s, dot, mse, j);
  elem_row<7>(d, t, s, dot, mse, j);
  elem_row<8>(d, t, s, dot, mse, j);
  elem_row<9>(d, t, s, dot, mse, j);
  elem_row<10>(d, t, s, dot, mse, j);

  // quad allreduce: 34 + 2 independent shuffles
  dot += __shfl_xor(dot, 1, 64);
  dot += __shfl_xor(dot, 2, 64);
#pragma unroll
  for (int k = 0; k < 17; ++k) {
    s[k] += __shfl_xor(s[k], 1, 64);
    s[k] += __shfl_xor(s[k], 2, 64);
  }
  float ce = -dot;
#pragma unroll
  for (int k = 0; k < 17; ++k) ce += __logf(s[k]);

  // ce replicated across quad -> count once; mask invalid rows.
  ce  = (valid && j == 0) ? ce : 0.0f;
  mse = valid ? mse : 0.0f;

  __shared__ float sm[4], sc[4];
#pragma unroll
  for (int off = 32; off > 0; off >>= 1) {
    mse += __shfl_down(mse, off, 64);
    ce  += __shfl_down(ce, off, 64);
  }
  if (lane == 0) { sm[wid] = mse; sc[wid] = ce; }
  __syncthreads();
  if (threadIdx.x == 0) {
    const int slot = (blockIdx.x & 63) * 32;   // 128B-padded slots, 64-way spread
    atomicAdd(&wsf[SUM2_OFF + slot], sm[0] + sm[1] + sm[2] + sm[3]);
    atomicAdd(&wsf[SUM2_CE  + slot], sc[0] + sc[1] + sc[2] + sc[3]);
  }
}

__global__ __launch_bounds__(256) void k_final(const unsigned* __restrict__ ws,
                                               float* __restrict__ out, int B) {
  const float* wsf = (const float*)ws;
  float male   = (float)ws[CNT_OFF + 0];
  float female = (float)ws[CNT_OFF + 1];
  float local = 0.0f;
  for (int i = threadIdx.x; i < NHCOLS * BINS; i += blockDim.x) {
    float mh  = (float)ws[MH_OFF + i] / male;
    float fh  = (float)ws[FH_OFF + i] / female;
    float mid = 0.5f * (mh + fh);
    if (mh > 0.0f) local += mh * logf((mh + 1e-12f) / (mid + 1e-12f));
    if (fh > 0.0f) local += fh * logf((fh + 1e-12f) / (mid + 1e-12f));
  }
  int lane = threadIdx.x & 63, wid = threadIdx.x >> 6;
  // mse/ce staging slots: wave 0 reduces 64 slots in parallel
  float msep = 0.0f, cep = 0.0f;
  if (threadIdx.x < 64) {
    msep = wsf[SUM2_OFF + threadIdx.x * 32];
    cep  = wsf[SUM2_CE  + threadIdx.x * 32];
  }
  __shared__ float s[4], sm2, sc2;
#pragma unroll
  for (int off = 32; off > 0; off >>= 1) {
    local += __shfl_down(local, off, 64);
    msep  += __shfl_down(msep, off, 64);
    cep   += __shfl_down(cep, off, 64);
  }
  if (lane == 0) s[wid] = local;
  if (threadIdx.x == 0) { sm2 = msep; sc2 = cep; }
  __syncthreads();
  if (threadIdx.x == 0) {
    float kld   = 0.5f * (s[0] + s[1] + s[2] + s[3]);
    float mse   = sm2 / (float)B;
    float ce    = sc2 / (float)B;
    float multi = 0.9f * (mse + ce) + 0.1f * kld;
    out[0] = multi;
    out[1] = mse;
    out[2] = ce;
    out[3] = 0.1f * kld;
  }
}

extern "C" void kernel_launch(void* const* d_in, const int* in_sizes, int n_in,
                              void* d_out, int out_size, void* d_ws, size_t ws_size,
                              hipStream_t stream) {
  (void)n_in; (void)out_size; (void)ws_size;
  const float* enc = (const float*)d_in[0];
  const float* dec = (const float*)d_in[1];
  const float* tru = (const float*)d_in[2];
  const float* lab = (const float*)d_in[3];
  const int B = in_sizes[3];                 // label_true is [B,1]
  unsigned* ws = (unsigned*)d_ws;
  float* out = (float*)d_out;

  hipLaunchKernelGGL(k_init, dim3((WS_TOTAL_U32 + 255) / 256), dim3(256), 0, stream, ws);
  hipLaunchKernelGGL(k_minmax, dim3(352), dim3(256), 0, stream, enc, lab, ws, B);
  hipLaunchKernelGGL(k_hist, dim3(HBLK), dim3(256), 0, stream, enc, lab, ws, B);
  hipLaunchKernelGGL(k_main, dim3((B + 63) / 64), dim3(256), 0, stream,
                     dec, tru, (float*)ws, B);
  hipLaunchKernelGGL(k_final, dim3(1), dim3(256), 0, stream, ws, out, B);
}